// Round 7
// baseline (205.104 us; speedup 1.0000x reference)
//
#include <hip/hip_runtime.h>
#include <hip/hip_bf16.h>

// Problem constants (b=2, l=4, n=1024, dim=512, heads=8, dh=64, nsample=8)
// All d_in / d_out buffers are FLOAT32 (reference dtypes). Internal compute
// uses bf16 MFMA (allowed by the bf16-mode absmax threshold 0.105).
#define B_ 2
#define L_ 4
#define N_ 1024
#define DIM_ 512
#define INNER_ 512
#define HEADS_ 8
#define DH_ 64
#define NS_ 8
#define NFR_ (B_ * L_)            // 8 flat frames
#define ROWS_ (B_ * L_ * N_)      // 8192 point rows

typedef unsigned short u16;
typedef __attribute__((ext_vector_type(8))) short bf16x8;
typedef __attribute__((ext_vector_type(4))) float f32x4;

__device__ inline float bf2f(u16 u) {
    union { unsigned i; float f; } c; c.i = ((unsigned)u) << 16; return c.f;
}
__device__ inline float bflo(unsigned v) {   // low bf16 of dword -> f32
    union { unsigned i; float f; } c; c.i = v << 16; return c.f;
}
__device__ inline float bfhi(unsigned v) {   // high bf16 of dword -> f32
    union { unsigned i; float f; } c; c.i = v & 0xffff0000u; return c.f;
}
__device__ inline u16 f2bf(float x) {
    __hip_bfloat16 h = __float2bfloat16(x);  // round-to-nearest-even
    return *reinterpret_cast<u16*>(&h);
}

// Async global->LDS DMA, 16B per lane.  HW writes wave-uniform LDS base +
// lane*16; the lds pointer below must be computed so that consecutive lanes
// land at consecutive 16B slots (linear layout, NO padding - rule #21).
__device__ inline void load_lds16(const void* g, void* l) {
    __builtin_amdgcn_global_load_lds(
        (const __attribute__((address_space(1))) unsigned*)g,
        (__attribute__((address_space(3))) unsigned*)l, 16, 0, 0);
}

// 8-element bf16 dot with f32 accumulate; v_dot2_f32_bf16 when available.
#if __has_builtin(__builtin_amdgcn_fdot2_f32_bf16)
typedef __bf16 bf2v __attribute__((ext_vector_type(2)));
__device__ inline float dot8(bf16x8 a, bf16x8 b, float acc) {
    union U { bf16x8 v; bf2v p[4]; };
    U ua, ub; ua.v = a; ub.v = b;
    #pragma unroll
    for (int i = 0; i < 4; ++i)
        acc = __builtin_amdgcn_fdot2_f32_bf16(ua.p[i], ub.p[i], acc, false);
    return acc;
}
#else
__device__ inline float dot8(bf16x8 a, bf16x8 b, float acc) {
    #pragma unroll
    for (int e = 0; e < 8; ++e) acc += bf2f((u16)a[e]) * bf2f((u16)b[e]);
    return acc;
}
#endif

#define RPAD_(r) ((r) + ((r) >> 4))

// ---------------------------------------------------------------------------
// K0: fused prep kernel — transpose_cvt + layernorm + ball query.
//   blocks [0,256)            : weight transpose+cvt (0..191 wqkv, 192..255 wout)
//   blocks [256, 256+8192)    : LN row (b-256)
//   blocks [8448, 8448+2048)  : ballq block (b-8448)
// ---------------------------------------------------------------------------
__global__ __launch_bounds__(256) void prep_kernel(
    const float* __restrict__ wqkv, const float* __restrict__ wout,
    u16* __restrict__ wqkvT, u16* __restrict__ woutT,
    const float* __restrict__ feat, const float* __restrict__ gamma,
    const float* __restrict__ beta, u16* __restrict__ normf,
    const float* __restrict__ xyz, int* __restrict__ idxt)
{
    __shared__ union {
        float tile[64][65];                               // transpose: 16640 B
        struct { float rx[1088], ry[1088], rz[1088]; } bq; // ballq: 13056 B
        float red[4];                                     // ln
    } sm;

    int blk = blockIdx.x;
    int t = threadIdx.x;

    if (blk < 256) {
        // ---- weight transpose + bf16 cast (64x64 tile, pad 65) ----
        const float* src; u16* dst; int R, C, tr, tc;
        int b = blk;
        if (b < 192) { src = wqkv; dst = wqkvT; R = 512; C = 1536; tr = b / 24; tc = b % 24; }
        else { b -= 192; src = wout; dst = woutT; R = 512; C = 512; tr = b / 8; tc = b % 8; }
        int r0 = tr * 64, c0 = tc * 64;

        int rr = t >> 2, cs = (t & 3) * 16;
        const float* sp = src + (size_t)(r0 + rr) * C + c0 + cs;
        #pragma unroll
        for (int e = 0; e < 16; e += 4) {
            f32x4 v = *(const f32x4*)(sp + e);
            sm.tile[rr][cs + e + 0] = v[0];
            sm.tile[rr][cs + e + 1] = v[1];
            sm.tile[rr][cs + e + 2] = v[2];
            sm.tile[rr][cs + e + 3] = v[3];
        }
        __syncthreads();

        int c = t >> 2, ks = (t & 3) * 16;
        u16 outv[16];
        #pragma unroll
        for (int e = 0; e < 16; ++e) outv[e] = f2bf(sm.tile[ks + e][c]);
        u16* dp = dst + (size_t)(c0 + c) * R + r0 + ks;
        *(bf16x8*)(dp)     = *(bf16x8*)&outv[0];
        *(bf16x8*)(dp + 8) = *(bf16x8*)&outv[8];

    } else if (blk < 256 + ROWS_) {
        // ---- LayerNorm over channel dim (512) -> bf16 ----
        int row = blk - 256;
        const float* fr = feat + (size_t)row * DIM_;
        float x0 = fr[t], x1 = fr[t + 256];

        float s = x0 + x1;
        #pragma unroll
        for (int off = 32; off; off >>= 1) s += __shfl_xor(s, off, 64);
        if ((t & 63) == 0) sm.red[t >> 6] = s;
        __syncthreads();
        float mu = (sm.red[0] + sm.red[1] + sm.red[2] + sm.red[3]) * (1.0f / 512.0f);
        __syncthreads();

        float d0 = x0 - mu, d1 = x1 - mu;
        float q = d0 * d0 + d1 * d1;
        #pragma unroll
        for (int off = 32; off; off >>= 1) q += __shfl_xor(q, off, 64);
        if ((t & 63) == 0) sm.red[t >> 6] = q;
        __syncthreads();
        float var = (sm.red[0] + sm.red[1] + sm.red[2] + sm.red[3]) * (1.0f / 512.0f);
        float inv = rsqrtf(var + 1e-5f);

        normf[(size_t)row * DIM_ + t]       = f2bf(d0 * inv * gamma[t]       + beta[t]);
        normf[(size_t)row * DIM_ + t + 256] = f2bf(d1 * inv * gamma[t + 256] + beta[t + 256]);

    } else {
        // ---- ball query (wave-parallel, staging-amortized) ----
        #pragma clang fp contract(off)
        int bb = blk - (256 + ROWS_);
        int chunk = bb & 255;           // 2048 blocks: (bi*4+jf)*256 + chunk
        int combo = bb >> 8;
        int jf = combo & 3;
        int bi = combo >> 2;

        const float* ref = xyz + (size_t)((bi * L_ + jf) * N_) * 3;
        for (int p = t; p < N_; p += 256) {
            sm.bq.rx[RPAD_(p)] = ref[p * 3 + 0];
            sm.bq.ry[RPAD_(p)] = ref[p * 3 + 1];
            sm.bq.rz[RPAD_(p)] = ref[p * 3 + 2];
        }
        __syncthreads();

        int wave = t >> 6;
        int lane = t & 63;
        int n = chunk * 4 + wave;
        int base = lane * 17;           // RPAD_(lane*16)
        int r0 = lane * 16;

        for (int qi = 0; qi < L_; ++qi) {
            const float* qp = xyz + (size_t)((bi * L_ + qi) * N_ + n) * 3;
            float qx = qp[0], qy = qp[1], qz = qp[2];

            unsigned mask = 0;
            #pragma unroll
            for (int j = 0; j < 16; ++j) {
                float dx = qx - sm.bq.rx[base + j];
                float dy = qy - sm.bq.ry[base + j];
                float dz = qz - sm.bq.rz[base + j];
                float d2 = dx * dx + dy * dy;
                d2 = d2 + dz * dz;
                if (d2 < 0.04f) mask |= (1u << j);
            }

            int cnt = __popc(mask);
            int x = cnt;
            #pragma unroll
            for (int off = 1; off < 64; off <<= 1) {
                int y = __shfl_up(x, off, 64);
                if (lane >= off) x += y;
            }
            int pre = x - cnt;                       // exclusive prefix
            int total = __shfl(x, 63, 64);           // total in-radius count

            int localFirst = mask ? (r0 + __builtin_ctz(mask)) : 0x7fffffff;
            int gfirst = localFirst;
            #pragma unroll
            for (int off = 32; off; off >>= 1) gfirst = min(gfirst, __shfl_xor(gfirst, off, 64));

            int* o = idxt + ((size_t)((qi * B_ + bi) * N_ + n)) * 32 + jf * NS_;

            unsigned m = mask;
            int pos = pre;
            while (m && pos < NS_) {
                int j = __builtin_ctz(m);
                o[pos] = r0 + j;
                m &= m - 1;
                ++pos;
            }
            if (lane == 0) {
                int padv = (total > 0) ? gfirst : 0;
                for (int s = (total < NS_ ? total : NS_); s < NS_; ++s) o[s] = padv;
            }
        }
    }
}

// ---------------------------------------------------------------------------
// K2/K5: MFMA bf16 GEMM, C[M,N] = A[M,K] @ Bt[N,K]^T.
// 128x128 block tile, BK=32, 256 threads (4 waves, each 64x64).
// Staging via global_load_lds dwordx4; LDS LINEAR [128][32].
// mode 0: Cb16 = bf16(acc)                          (qkv, bf16 ws)
// mode 1: Cf32 = gelu(acc + bias) + resid           (final output, f32)
// ---------------------------------------------------------------------------
__global__ __launch_bounds__(256) void gemm_bt(
    const u16* __restrict__ A, const u16* __restrict__ Bt,
    u16* __restrict__ Cb16, float* __restrict__ Cf32,
    int M, int N, int K, int nb128, int mode,
    const float* __restrict__ bias, const float* __restrict__ resid)
{
    __shared__ u16 As[128 * 32];   // linear, 8 KB
    __shared__ u16 Bs[128 * 32];

    int bx = blockIdx.x % nb128;
    int by = blockIdx.x / nb128;
    int m0 = by * 128, n0 = bx * 128;
    int t = threadIdx.x;
    int wave = t >> 6, lane = t & 63;
    int lr = lane & 15, quad = lane >> 4;
    int wm = (wave >> 1) * 64, wn = (wave & 1) * 64;

    f32x4 acc[4][4];
    #pragma unroll
    for (int i = 0; i < 4; ++i)
        #pragma unroll
        for (int j = 0; j < 4; ++j)
            acc[i][j] = {0.f, 0.f, 0.f, 0.f};

    for (int k0 = 0; k0 < K; k0 += 32) {
        #pragma unroll
        for (int p = 0; p < 2; ++p) {
            int c = t + p * 256;           // 0..511
            int r = c >> 2;                // 0..127
            int kc = (c & 3) * 8;          // 0,8,16,24
            load_lds16(A  + (size_t)(m0 + r) * K + k0 + kc, &As[c * 8]);
            load_lds16(Bt + (size_t)(n0 + r) * K + k0 + kc, &Bs[c * 8]);
        }
        __syncthreads();   // compiler emits s_waitcnt vmcnt(0) before barrier

        bf16x8 af[4], bfr[4];
        #pragma unroll
        for (int mb = 0; mb < 4; ++mb)
            af[mb] = *(const bf16x8*)&As[(wm + mb * 16 + lr) * 32 + quad * 8];
        #pragma unroll
        for (int nb = 0; nb < 4; ++nb)
            bfr[nb] = *(const bf16x8*)&Bs[(wn + nb * 16 + lr) * 32 + quad * 8];
        #pragma unroll
        for (int mb = 0; mb < 4; ++mb)
            #pragma unroll
            for (int nb = 0; nb < 4; ++nb)
                acc[mb][nb] = __builtin_amdgcn_mfma_f32_16x16x32_bf16(
                    af[mb], bfr[nb], acc[mb][nb], 0, 0, 0);
        __syncthreads();
    }

    #pragma unroll
    for (int mb = 0; mb < 4; ++mb) {
        #pragma unroll
        for (int nb = 0; nb < 4; ++nb) {
            int col = n0 + wn + nb * 16 + lr;
            #pragma unroll
            for (int r = 0; r < 4; ++r) {
                int row = m0 + wm + mb * 16 + quad * 4 + r;
                float x = acc[mb][nb][r];
                if (mode == 1) {
                    x += bias[col];
                    float gl = 0.5f * x * (1.0f + erff(x * 0.70710678118654752f));
                    Cf32[(size_t)row * N + col] = gl + resid[(size_t)row * N + col];
                } else {
                    Cb16[(size_t)row * N + col] = f2bf(x);
                }
            }
        }
    }
}

// ---------------------------------------------------------------------------
// K4: attention, round 14: FRAME-PHASED gather for L2 residency.
// r12 (V reorder) and r13 (2 queries/block) were both neutral => attn is
// BANDWIDTH-bound on the gather path, not latency-bound: 533 MB of K/V
// gathers served at ~15 TB/s = the L3 tier.  Cause: wave w owned slots
// w*8..w*8+7 = frame jf=w, so each block touched ALL 4 ref frames of bi
// simultaneously -> 8 MB working set per XCD > 4 MB L2 -> L3.
// Fix: loop jf phases; in phase jf ALL waves gather only frame (bi,jf):
// wave w -> query (w>>1), slots jf*8 + (w&1)*4 + {0..3} (4 K rows/wave),
// plus that frame's 16 V dwords into the persistent vv regs (static
// indices, fully unrolled).  Per-XCD working set per phase: 2 MB -> L2.
// Same bytes, same per-slot math, softmax/PV unchanged.  Peak VGPR ~108
// (kf is 4 rows, not 16) < 128 cap of (256,4).
// ---------------------------------------------------------------------------
__global__ __launch_bounds__(256, 4) void attn_kernel(
    const float* __restrict__ xyz, const u16* __restrict__ qkv,
    const int* __restrict__ idxt, const float* __restrict__ wsp,
    u16* __restrict__ fres)
{
    int x = blockIdx.x & 7;             // XCD swizzle: (bi,qi) per XCD
    int bi = x >> 2;
    int qi = x & 3;
    int n0 = (blockIdx.x >> 3) * 2;     // queries n0 and n0+1

    int t = threadIdx.x;
    int wave = t >> 6, lane = t & 63;

    int qrow0 = (bi * L_ + qi) * N_ + n0;                // xyz/qkv rows
    int qrow1 = qrow0 + 1;
    int qq0 = (qi * B_ + bi) * N_ + n0;                  // idxt rows

    __shared__ int grow_s[2][32];
    __shared__ float nx_s[2][32], ny_s[2][32], nz_s[2][32];
    __shared__ float lg_s[2][HEADS_][33];                // pad 33: conflict-free
    __shared__ float a_s[2][HEADS_][32];
    __shared__ float da_s[2][HEADS_][3];

    // Per-lane Q fragments (block-uniform rows => SGPR base, 1 KB coalesced).
    bf16x8 qf0 = *(const bf16x8*)(qkv + (size_t)qrow0 * 1536 + lane * 8);
    bf16x8 qf1 = *(const bf16x8*)(qkv + (size_t)qrow1 * 1536 + lane * 8);

    // 64 lanes resolve BOTH queries' gathered rows + neighbor xyz at once.
    if (t < 64) {
        int qsel = t >> 5, tt = t & 31;
        int idx = idxt[(size_t)(qq0 + qsel) * 32 + tt];  // one 256B coalesced load
        int jf = tt >> 3;
        int kr = (bi * L_ + jf) * N_ + idx;
        grow_s[qsel][tt] = kr;
        nx_s[qsel][tt] = xyz[(size_t)kr * 3 + 0];
        ny_s[qsel][tt] = xyz[(size_t)kr * 3 + 1];
        nz_s[qsel][tt] = xyz[(size_t)kr * 3 + 2];
    }
    __syncthreads();

    int hh = lane >> 5;
    int j = lane & 31;
    int h = wave * 2 + hh;
    int dd = j * 2;
    unsigned vbyte = (1024u + (unsigned)h * 64u + (unsigned)dd) * 2u;

    int qsel = wave >> 1;                 // waves 0,1 -> q0; waves 2,3 -> q1
    bf16x8 qfd = qsel ? qf1 : qf0;        // wave-uniform select
    unsigned vv0[32], vv1[32];

    // --- frame-phased gather + QK^T.  Phase jf touches ONLY frame (bi,jf).
    #pragma unroll
    for (int jf = 0; jf < 4; ++jf) {
        int s0 = jf * 8 + (wave & 1) * 4;
        // 4 coalesced 1 KB K-row loads for this wave's (query, slot-quad)
        bf16x8 kf[4];
        #pragma unroll
        for (int r = 0; r < 4; ++r) {
            int kr = __builtin_amdgcn_readfirstlane(grow_s[qsel][s0 + r]);
            kf[r] = *(const bf16x8*)((const char*)qkv + (size_t)kr * 3072 + 1024 + lane * 16);
        }
        // this frame's V dwords (8 slots x 2 queries) into persistent regs
        #pragma unroll
        for (int s = 0; s < 8; ++s) {
            int r0v = __builtin_amdgcn_readfirstlane(grow_s[0][jf * 8 + s]);
            vv0[jf * 8 + s] = *(const unsigned*)((const char*)qkv + (size_t)r0v * 3072 + vbyte);
            int r1v = __builtin_amdgcn_readfirstlane(grow_s[1][jf * 8 + s]);
            vv1[jf * 8 + s] = *(const unsigned*)((const char*)qkv + (size_t)r1v * 3072 + vbyte);
        }
        __builtin_amdgcn_sched_barrier(0);   // K+V of this phase issued first
        // dots: 8-dim partials reduced across the 8-lane head group
        #pragma unroll
        for (int r = 0; r < 4; ++r) {
            float p = dot8(kf[r], qfd, 0.f);
            p += __shfl_xor(p, 1, 64);
            p += __shfl_xor(p, 2, 64);
            p += __shfl_xor(p, 4, 64);
            if ((lane & 7) == 0) lg_s[qsel][lane >> 3][s0 + r] = p * 0.125f;
        }
    }

    __syncthreads();

    // --- softmax + disp-max, original (h, j) lane mapping, both queries ---
    #pragma unroll
    for (int q = 0; q < 2; ++q) {
        float lg = lg_s[q][h][j];
        float mx = lg;
        #pragma unroll
        for (int off = 16; off; off >>= 1) mx = fmaxf(mx, __shfl_xor(mx, off, 64));
        float e = expf(lg - mx);
        float sum = e;
        #pragma unroll
        for (int off = 16; off; off >>= 1) sum += __shfl_xor(sum, off, 64);
        float a = e / sum;
        a_s[q][h][j] = a;

        int qrow = qrow0 + q;
        float qx = xyz[(size_t)qrow * 3 + 0];
        float qy = xyz[(size_t)qrow * 3 + 1];
        float qz = xyz[(size_t)qrow * 3 + 2];
        float tx = a * (nx_s[q][j] - qx);
        float ty = a * (ny_s[q][j] - qy);
        float tz = a * (nz_s[q][j] - qz);
        #pragma unroll
        for (int off = 16; off; off >>= 1) {
            tx = fmaxf(tx, __shfl_xor(tx, off, 64));
            ty = fmaxf(ty, __shfl_xor(ty, off, 64));
            tz = fmaxf(tz, __shfl_xor(tz, off, 64));
        }
        if (j == 0) { da_s[q][h][0] = tx; da_s[q][h][1] = ty; da_s[q][h][2] = tz; }
    }

    __syncthreads();

    // --- PV accumulate + spatial op + store, both queries ---
    float w0 = wsp[dd],     w1 = wsp[64 + dd],     w2 = wsp[128 + dd];
    float w3 = wsp[dd + 1], w4 = wsp[64 + dd + 1], w5 = wsp[128 + dd + 1];

    {
        float o0 = 0.f, o1 = 0.f;
        #pragma unroll
        for (int s = 0; s < 32; ++s) {
            float at = a_s[0][h][s];
            o0 += at * bflo(vv0[s]);
            o1 += at * bfhi(vv0[s]);
        }
        float dax = da_s[0][h][0], day = da_s[0][h][1], daz = da_s[0][h][2];
        float sp0 = dax * w0 + day * w1 + daz * w2;
        float sp1 = dax * w3 + day * w4 + daz * w5;
        u16* op = fres + (size_t)qrow0 * INNER_ + h * 64 + dd;
        *(unsigned*)op = (unsigned)f2bf(o0 + sp0) | ((unsigned)f2bf(o1 + sp1) << 16);
    }
    {
        float o0 = 0.f, o1 = 0.f;
        #pragma unroll
        for (int s = 0; s < 32; ++s) {
            float at = a_s[1][h][s];
            o0 += at * bflo(vv1[s]);
            o1 += at * bfhi(vv1[s]);
        }
        float dax = da_s[1][h][0], day = da_s[1][h][1], daz = da_s[1][h][2];
        float sp0 = dax * w0 + day * w1 + daz * w2;
        float sp1 = dax * w3 + day * w4 + daz * w5;
        u16* op = fres + (size_t)qrow1 * INNER_ + h * 64 + dd;
        *(unsigned*)op = (unsigned)f2bf(o0 + sp0) | ((unsigned)f2bf(o1 + sp1) << 16);
    }
}

// ---------------------------------------------------------------------------
extern "C" void kernel_launch(void* const* d_in, const int* in_sizes, int n_in,
                              void* d_out, int out_size, void* d_ws, size_t ws_size,
                              hipStream_t stream) {
    const float* xyz   = (const float*)d_in[0];   // (2,4,1024,3)
    const float* feat  = (const float*)d_in[1];   // (2,4,1024,512)
    const float* gamma = (const float*)d_in[2];   // (512)
    const float* beta  = (const float*)d_in[3];   // (512)
    const float* wqkv  = (const float*)d_in[4];   // (512,1536)
    const float* wsp   = (const float*)d_in[5];   // (3,64)
    const float* wout  = (const float*)d_in[6];   // (512,512)
    const float* bout  = (const float*)d_in[7];   // (512)
    float* out = (float*)d_out;

    char* ws = (char*)d_ws;
    u16* normf = (u16*)ws;                 ws += (size_t)ROWS_ * DIM_ * 2;        // 8 MB
    u16* wqkvT = (u16*)ws;                 ws += (size_t)3 * INNER_ * DIM_ * 2;   // 1.5 MB
    u16* woutT = (u16*)ws;                 ws += (size_t)DIM_ * INNER_ * 2;       // 0.5 MB
    u16* qkv   = (u16*)ws;                 ws += (size_t)ROWS_ * 3 * INNER_ * 2;  // 24 MB
    int* idxt  = (int*)ws;                 ws += (size_t)L_ * NFR_ * N_ * NS_ * 4;// 1 MB
    u16* fres  = normf;   // alias: normf is dead after GEMM1 completes

    // prep: transpose+cvt (256 blocks) | layernorm (8192) | ball query (2048)
    prep_kernel<<<256 + ROWS_ + 2048, 256, 0, stream>>>(
        wqkv, wout, wqkvT, woutT, feat, gamma, beta, normf, xyz, idxt);
    // qkv = normf @ w_qkv : M=8192, N=1536, K=512
    gemm_bt<<<64 * 12, 256, 0, stream>>>(normf, wqkvT, qkv, nullptr,
                                         ROWS_, 3 * INNER_, DIM_, 12, 0, nullptr, nullptr);
    // attention: 2 queries per block, frame-phased gather
    attn_kernel<<<ROWS_ / 2, 256, 0, stream>>>(xyz, qkv, idxt, wsp, fres);
    // out = gelu(fres @ w_out + b_out) + feature : M=8192, N=512, K=512
    gemm_bt<<<64 * 4, 256, 0, stream>>>(fres, woutT, nullptr, out,
                                        ROWS_, DIM_, INNER_, 4, 1, bout, feat);
}

// Round 8
// 196.878 us; speedup vs baseline: 1.0418x; 1.0418x over previous
//
#include <hip/hip_runtime.h>
#include <hip/hip_bf16.h>

// Problem constants (b=2, l=4, n=1024, dim=512, heads=8, dh=64, nsample=8)
// All d_in / d_out buffers are FLOAT32 (reference dtypes). Internal compute
// uses bf16 MFMA (allowed by the bf16-mode absmax threshold 0.105).
#define B_ 2
#define L_ 4
#define N_ 1024
#define DIM_ 512
#define INNER_ 512
#define HEADS_ 8
#define DH_ 64
#define NS_ 8
#define NFR_ (B_ * L_)            // 8 flat frames
#define ROWS_ (B_ * L_ * N_)      // 8192 point rows

typedef unsigned short u16;
typedef __attribute__((ext_vector_type(8))) short bf16x8;
typedef __attribute__((ext_vector_type(4))) float f32x4;

__device__ inline float bf2f(u16 u) {
    union { unsigned i; float f; } c; c.i = ((unsigned)u) << 16; return c.f;
}
__device__ inline float bflo(unsigned v) {   // low bf16 of dword -> f32
    union { unsigned i; float f; } c; c.i = v << 16; return c.f;
}
__device__ inline float bfhi(unsigned v) {   // high bf16 of dword -> f32
    union { unsigned i; float f; } c; c.i = v & 0xffff0000u; return c.f;
}
__device__ inline u16 f2bf(float x) {
    __hip_bfloat16 h = __float2bfloat16(x);  // round-to-nearest-even
    return *reinterpret_cast<u16*>(&h);
}

// Async global->LDS DMA, 16B per lane.  HW writes wave-uniform LDS base +
// lane*16; the lds pointer below must be computed so that consecutive lanes
// land at consecutive 16B slots (linear layout, NO padding - rule #21).
__device__ inline void load_lds16(const void* g, void* l) {
    __builtin_amdgcn_global_load_lds(
        (const __attribute__((address_space(1))) unsigned*)g,
        (__attribute__((address_space(3))) unsigned*)l, 16, 0, 0);
}

// 8-element bf16 dot with f32 accumulate; v_dot2_f32_bf16 when available.
#if __has_builtin(__builtin_amdgcn_fdot2_f32_bf16)
typedef __bf16 bf2v __attribute__((ext_vector_type(2)));
__device__ inline float dot8(bf16x8 a, bf16x8 b, float acc) {
    union U { bf16x8 v; bf2v p[4]; };
    U ua, ub; ua.v = a; ub.v = b;
    #pragma unroll
    for (int i = 0; i < 4; ++i)
        acc = __builtin_amdgcn_fdot2_f32_bf16(ua.p[i], ub.p[i], acc, false);
    return acc;
}
#else
__device__ inline float dot8(bf16x8 a, bf16x8 b, float acc) {
    #pragma unroll
    for (int e = 0; e < 8; ++e) acc += bf2f((u16)a[e]) * bf2f((u16)b[e]);
    return acc;
}
#endif

#define RPAD_(r) ((r) + ((r) >> 4))

// ---------------------------------------------------------------------------
// K0: fused prep kernel — transpose_cvt + layernorm + ball query.
//   blocks [0,256)            : weight transpose+cvt (0..191 wqkv, 192..255 wout)
//   blocks [256, 256+8192)    : LN row (b-256)
//   blocks [8448, 8448+2048)  : ballq block (b-8448)
// ---------------------------------------------------------------------------
__global__ __launch_bounds__(256) void prep_kernel(
    const float* __restrict__ wqkv, const float* __restrict__ wout,
    u16* __restrict__ wqkvT, u16* __restrict__ woutT,
    const float* __restrict__ feat, const float* __restrict__ gamma,
    const float* __restrict__ beta, u16* __restrict__ normf,
    const float* __restrict__ xyz, int* __restrict__ idxt)
{
    __shared__ union {
        float tile[64][65];                               // transpose: 16640 B
        struct { float rx[1088], ry[1088], rz[1088]; } bq; // ballq: 13056 B
        float red[4];                                     // ln
    } sm;

    int blk = blockIdx.x;
    int t = threadIdx.x;

    if (blk < 256) {
        // ---- weight transpose + bf16 cast (64x64 tile, pad 65) ----
        const float* src; u16* dst; int R, C, tr, tc;
        int b = blk;
        if (b < 192) { src = wqkv; dst = wqkvT; R = 512; C = 1536; tr = b / 24; tc = b % 24; }
        else { b -= 192; src = wout; dst = woutT; R = 512; C = 512; tr = b / 8; tc = b % 8; }
        int r0 = tr * 64, c0 = tc * 64;

        int rr = t >> 2, cs = (t & 3) * 16;
        const float* sp = src + (size_t)(r0 + rr) * C + c0 + cs;
        #pragma unroll
        for (int e = 0; e < 16; e += 4) {
            f32x4 v = *(const f32x4*)(sp + e);
            sm.tile[rr][cs + e + 0] = v[0];
            sm.tile[rr][cs + e + 1] = v[1];
            sm.tile[rr][cs + e + 2] = v[2];
            sm.tile[rr][cs + e + 3] = v[3];
        }
        __syncthreads();

        int c = t >> 2, ks = (t & 3) * 16;
        u16 outv[16];
        #pragma unroll
        for (int e = 0; e < 16; ++e) outv[e] = f2bf(sm.tile[ks + e][c]);
        u16* dp = dst + (size_t)(c0 + c) * R + r0 + ks;
        *(bf16x8*)(dp)     = *(bf16x8*)&outv[0];
        *(bf16x8*)(dp + 8) = *(bf16x8*)&outv[8];

    } else if (blk < 256 + ROWS_) {
        // ---- LayerNorm over channel dim (512) -> bf16 ----
        int row = blk - 256;
        const float* fr = feat + (size_t)row * DIM_;
        float x0 = fr[t], x1 = fr[t + 256];

        float s = x0 + x1;
        #pragma unroll
        for (int off = 32; off; off >>= 1) s += __shfl_xor(s, off, 64);
        if ((t & 63) == 0) sm.red[t >> 6] = s;
        __syncthreads();
        float mu = (sm.red[0] + sm.red[1] + sm.red[2] + sm.red[3]) * (1.0f / 512.0f);
        __syncthreads();

        float d0 = x0 - mu, d1 = x1 - mu;
        float q = d0 * d0 + d1 * d1;
        #pragma unroll
        for (int off = 32; off; off >>= 1) q += __shfl_xor(q, off, 64);
        if ((t & 63) == 0) sm.red[t >> 6] = q;
        __syncthreads();
        float var = (sm.red[0] + sm.red[1] + sm.red[2] + sm.red[3]) * (1.0f / 512.0f);
        float inv = rsqrtf(var + 1e-5f);

        normf[(size_t)row * DIM_ + t]       = f2bf(d0 * inv * gamma[t]       + beta[t]);
        normf[(size_t)row * DIM_ + t + 256] = f2bf(d1 * inv * gamma[t + 256] + beta[t + 256]);

    } else {
        // ---- ball query (wave-parallel, staging-amortized) ----
        #pragma clang fp contract(off)
        int bb = blk - (256 + ROWS_);
        int chunk = bb & 255;           // 2048 blocks: (bi*4+jf)*256 + chunk
        int combo = bb >> 8;
        int jf = combo & 3;
        int bi = combo >> 2;

        const float* ref = xyz + (size_t)((bi * L_ + jf) * N_) * 3;
        for (int p = t; p < N_; p += 256) {
            sm.bq.rx[RPAD_(p)] = ref[p * 3 + 0];
            sm.bq.ry[RPAD_(p)] = ref[p * 3 + 1];
            sm.bq.rz[RPAD_(p)] = ref[p * 3 + 2];
        }
        __syncthreads();

        int wave = t >> 6;
        int lane = t & 63;
        int n = chunk * 4 + wave;
        int base = lane * 17;           // RPAD_(lane*16)
        int r0 = lane * 16;

        for (int qi = 0; qi < L_; ++qi) {
            const float* qp = xyz + (size_t)((bi * L_ + qi) * N_ + n) * 3;
            float qx = qp[0], qy = qp[1], qz = qp[2];

            unsigned mask = 0;
            #pragma unroll
            for (int j = 0; j < 16; ++j) {
                float dx = qx - sm.bq.rx[base + j];
                float dy = qy - sm.bq.ry[base + j];
                float dz = qz - sm.bq.rz[base + j];
                float d2 = dx * dx + dy * dy;
                d2 = d2 + dz * dz;
                if (d2 < 0.04f) mask |= (1u << j);
            }

            int cnt = __popc(mask);
            int x = cnt;
            #pragma unroll
            for (int off = 1; off < 64; off <<= 1) {
                int y = __shfl_up(x, off, 64);
                if (lane >= off) x += y;
            }
            int pre = x - cnt;                       // exclusive prefix
            int total = __shfl(x, 63, 64);           // total in-radius count

            int localFirst = mask ? (r0 + __builtin_ctz(mask)) : 0x7fffffff;
            int gfirst = localFirst;
            #pragma unroll
            for (int off = 32; off; off >>= 1) gfirst = min(gfirst, __shfl_xor(gfirst, off, 64));

            int* o = idxt + ((size_t)((qi * B_ + bi) * N_ + n)) * 32 + jf * NS_;

            unsigned m = mask;
            int pos = pre;
            while (m && pos < NS_) {
                int j = __builtin_ctz(m);
                o[pos] = r0 + j;
                m &= m - 1;
                ++pos;
            }
            if (lane == 0) {
                int padv = (total > 0) ? gfirst : 0;
                for (int s = (total < NS_ ? total : NS_); s < NS_; ++s) o[s] = padv;
            }
        }
    }
}

// ---------------------------------------------------------------------------
// K2/K5: MFMA bf16 GEMM, C[M,N] = A[M,K] @ Bt[N,K]^T.
// 128x128 block tile, BK=32, 256 threads (4 waves, each 64x64).
// Round 15: 2-phase double-buffered K-loop (guide T3 "minimum 2-phase").
// r7 profile: GEMM1 = 43 us, MfmaUtil 3.2%, HBM 12% -- the old
// STAGE->barrier->MFMA->barrier loop exposed the full ~900cy
// global_load_lds latency at each of 16 K-steps with only 3 blocks/CU of
// TLP.  Now tile kt+1 is staged into buf^1 BEFORE computing tile kt from
// buf; ONE __syncthreads per step (its implicit vmcnt(0) drains the
// prefetch after its latency overlapped compute).  LDS 2x16KB = 32 KB
// (LDS cap 5 blocks/CU > 3 resident -- no occupancy loss).
// mode 0: Cb16 = bf16(acc)                          (qkv, bf16 ws)
// mode 1: Cf32 = gelu(acc + bias) + resid           (final output, f32)
// ---------------------------------------------------------------------------
__global__ __launch_bounds__(256) void gemm_bt(
    const u16* __restrict__ A, const u16* __restrict__ Bt,
    u16* __restrict__ Cb16, float* __restrict__ Cf32,
    int M, int N, int K, int nb128, int mode,
    const float* __restrict__ bias, const float* __restrict__ resid)
{
    __shared__ u16 As[2][128 * 32];   // linear, 2 x 8 KB per operand
    __shared__ u16 Bs[2][128 * 32];

    int bx = blockIdx.x % nb128;
    int by = blockIdx.x / nb128;
    int m0 = by * 128, n0 = bx * 128;
    int t = threadIdx.x;
    int wave = t >> 6, lane = t & 63;
    int lr = lane & 15, quad = lane >> 4;
    int wm = (wave >> 1) * 64, wn = (wave & 1) * 64;

    // per-thread staging coords: element c = t + p*256 covers row c>>2,
    // 8-col chunk (c&3)*8; LDS u16 offset c*8 (linear match for the DMA).
    int r0s = t >> 2;            // rows for p=0 (0..63) ; p=1 adds 64
    int kcs = (t & 3) * 8;

    f32x4 acc[4][4];
    #pragma unroll
    for (int i = 0; i < 4; ++i)
        #pragma unroll
        for (int j = 0; j < 4; ++j)
            acc[i][j] = {0.f, 0.f, 0.f, 0.f};

    int NT = K >> 5;             // 16 K-steps for K=512

    // prologue: stage tile 0 into buf 0
    #pragma unroll
    for (int p = 0; p < 2; ++p) {
        int c = t + p * 256;
        int r = r0s + p * 64;
        load_lds16(A  + (size_t)(m0 + r) * K + kcs, &As[0][c * 8]);
        load_lds16(Bt + (size_t)(n0 + r) * K + kcs, &Bs[0][c * 8]);
    }
    __syncthreads();

    int cur = 0;
    for (int kt = 0; kt < NT; ++kt) {
        // issue next tile's staging FIRST (latency overlaps this tile's math)
        if (kt + 1 < NT) {
            int k0 = (kt + 1) << 5;
            #pragma unroll
            for (int p = 0; p < 2; ++p) {
                int c = t + p * 256;
                int r = r0s + p * 64;
                load_lds16(A  + (size_t)(m0 + r) * K + k0 + kcs, &As[cur ^ 1][c * 8]);
                load_lds16(Bt + (size_t)(n0 + r) * K + k0 + kcs, &Bs[cur ^ 1][c * 8]);
            }
        }

        bf16x8 af[4], bfr[4];
        #pragma unroll
        for (int mb = 0; mb < 4; ++mb)
            af[mb] = *(const bf16x8*)&As[cur][(wm + mb * 16 + lr) * 32 + quad * 8];
        #pragma unroll
        for (int nb = 0; nb < 4; ++nb)
            bfr[nb] = *(const bf16x8*)&Bs[cur][(wn + nb * 16 + lr) * 32 + quad * 8];
        #pragma unroll
        for (int mb = 0; mb < 4; ++mb)
            #pragma unroll
            for (int nb = 0; nb < 4; ++nb)
                acc[mb][nb] = __builtin_amdgcn_mfma_f32_16x16x32_bf16(
                    af[mb], bfr[nb], acc[mb][nb], 0, 0, 0);

        __syncthreads();   // implicit vmcnt(0)+lgkmcnt(0): prefetch landed,
                           // all waves done reading buf[cur]
        cur ^= 1;
    }

    #pragma unroll
    for (int mb = 0; mb < 4; ++mb) {
        #pragma unroll
        for (int nb = 0; nb < 4; ++nb) {
            int col = n0 + wn + nb * 16 + lr;
            #pragma unroll
            for (int r = 0; r < 4; ++r) {
                int row = m0 + wm + mb * 16 + quad * 4 + r;
                float x = acc[mb][nb][r];
                if (mode == 1) {
                    x += bias[col];
                    float gl = 0.5f * x * (1.0f + erff(x * 0.70710678118654752f));
                    Cf32[(size_t)row * N + col] = gl + resid[(size_t)row * N + col];
                } else {
                    Cb16[(size_t)row * N + col] = f2bf(x);
                }
            }
        }
    }
}

// ---------------------------------------------------------------------------
// K4: attention, request-coalesced (round-3 configuration, best-measured).
// r13 (2 queries/block) and r14 (frame-phased gather) were neutral-to-
// negative -> reverted.  The wave loads ONE K row (1 KB) per instruction
// from an SGPR base (readfirstlane on the LDS-held row id) + lane*16B
// voffset.  Lane l holds K[row][l*8..l*8+8) paired with a per-lane Q
// fragment; 3-step shfl_xor (1,2,4) reduces within each 8-lane head group.
// Logits bounce through padded LDS [8][33]; softmax/disp-max/PV unchanged.
// V gather SGPR-base addressed after softmax.
// ---------------------------------------------------------------------------
__global__ __launch_bounds__(256, 4) void attn_kernel(
    const float* __restrict__ xyz, const u16* __restrict__ qkv,
    const int* __restrict__ idxt, const float* __restrict__ wsp,
    u16* __restrict__ fres)
{
    int x = blockIdx.x & 7;             // XCD swizzle retained (FETCH 100->35 MB)
    int bi = x >> 2;
    int qi = x & 3;
    int n = blockIdx.x >> 3;

    int t = threadIdx.x;
    int wave = t >> 6, lane = t & 63;

    int qrow = (bi * L_ + qi) * N_ + n;                  // xyz/qkv row
    int qq = (qi * B_ + bi) * N_ + n;                    // idxt row

    __shared__ int grow_s[32];
    __shared__ float nx_s[32], ny_s[32], nz_s[32];
    __shared__ float lg_s[HEADS_][33];                   // pad 33: conflict-free
    __shared__ float a_s[HEADS_][32];
    __shared__ float da_s[HEADS_][3];

    // Per-lane Q fragment: lane l holds q[qrow][l*8 .. l*8+8) -> head l>>3.
    bf16x8 qf = *(const bf16x8*)(qkv + (size_t)qrow * 1536 + lane * 8);

    // 32 lanes resolve the gathered rows + neighbor xyz once per block.
    if (t < 32) {
        int idx = idxt[(size_t)qq * 32 + t];             // one coalesced 128B load
        int jf = t >> 3;
        int kr = (bi * L_ + jf) * N_ + idx;
        grow_s[t] = kr;
        nx_s[t] = xyz[(size_t)kr * 3 + 0];
        ny_s[t] = xyz[(size_t)kr * 3 + 1];
        nz_s[t] = xyz[(size_t)kr * 3 + 2];
    }
    __syncthreads();

    // --- QK^T: wave w owns neighbor slots j = w*8 + r.  One coalesced 1 KB
    // K-row load per slot (SGPR base + lane*16B), batched before use. ---
    bf16x8 kf[8];
    #pragma unroll
    for (int r = 0; r < 8; ++r) {
        int kr = __builtin_amdgcn_readfirstlane(grow_s[wave * 8 + r]);
        const char* kbase = (const char*)qkv + (size_t)kr * 3072 + 1024;  // K block
        kf[r] = *(const bf16x8*)(kbase + lane * 16);
    }
    __builtin_amdgcn_sched_barrier(0);   // all 8 row loads issued before use

    #pragma unroll
    for (int r = 0; r < 8; ++r) {
        float p = dot8(kf[r], qf, 0.f);
        p += __shfl_xor(p, 1, 64);       // reduce 8-dim partials within the
        p += __shfl_xor(p, 2, 64);       // 8-lane head group -> full dot64
        p += __shfl_xor(p, 4, 64);
        if ((lane & 7) == 0) lg_s[lane >> 3][wave * 8 + r] = p * 0.125f;  // dh^-0.5
    }
    __syncthreads();

    // --- softmax + disp-max in the original (h, j) lane mapping ---
    int hh = lane >> 5;
    int j = lane & 31;
    int h = wave * 2 + hh;

    float lg = lg_s[h][j];
    float mx = lg;
    #pragma unroll
    for (int off = 16; off; off >>= 1) mx = fmaxf(mx, __shfl_xor(mx, off, 64));
    float e = expf(lg - mx);
    float sum = e;
    #pragma unroll
    for (int off = 16; off; off >>= 1) sum += __shfl_xor(sum, off, 64);
    float a = e / sum;
    a_s[h][j] = a;

    float qx = xyz[(size_t)qrow * 3 + 0];
    float qy = xyz[(size_t)qrow * 3 + 1];
    float qz = xyz[(size_t)qrow * 3 + 2];
    float tx = a * (nx_s[j] - qx);
    float ty = a * (ny_s[j] - qy);
    float tz = a * (nz_s[j] - qz);
    #pragma unroll
    for (int off = 16; off; off >>= 1) {
        tx = fmaxf(tx, __shfl_xor(tx, off, 64));
        ty = fmaxf(ty, __shfl_xor(ty, off, 64));
        tz = fmaxf(tz, __shfl_xor(tz, off, 64));
    }
    if (j == 0) { da_s[h][0] = tx; da_s[h][1] = ty; da_s[h][2] = tz; }

    __syncthreads();

    // --- Phase C: V gather (coalesced), SGPR-base addressed. ---
    int dd = j * 2;
    unsigned vbyte = (1024u + (unsigned)h * 64u + (unsigned)dd) * 2u;  // V block col
    unsigned vv[32];
    #pragma unroll
    for (int s = 0; s < 32; ++s) {
        int r = __builtin_amdgcn_readfirstlane(grow_s[s]);
        const char* vbase = (const char*)qkv + (size_t)r * 3072;       // uniform
        vv[s] = *(const unsigned*)(vbase + vbyte);
    }
    __builtin_amdgcn_sched_barrier(0);   // all 32 loads issued before any use

    float o0 = 0.f, o1 = 0.f;
    #pragma unroll
    for (int s = 0; s < 32; ++s) {
        float at = a_s[h][s];
        o0 += at * bflo(vv[s]);
        o1 += at * bfhi(vv[s]);
    }
    float dax = da_s[h][0], day = da_s[h][1], daz = da_s[h][2];
    float sp0 = dax * wsp[dd]     + day * wsp[64 + dd]     + daz * wsp[128 + dd];
    float sp1 = dax * wsp[dd + 1] + day * wsp[64 + dd + 1] + daz * wsp[128 + dd + 1];

    u16* op = fres + (size_t)qrow * INNER_ + h * 64 + dd;
    unsigned outw = (unsigned)f2bf(o0 + sp0) | ((unsigned)f2bf(o1 + sp1) << 16);
    *(unsigned*)op = outw;
}

// ---------------------------------------------------------------------------
extern "C" void kernel_launch(void* const* d_in, const int* in_sizes, int n_in,
                              void* d_out, int out_size, void* d_ws, size_t ws_size,
                              hipStream_t stream) {
    const float* xyz   = (const float*)d_in[0];   // (2,4,1024,3)
    const float* feat  = (const float*)d_in[1];   // (2,4,1024,512)
    const float* gamma = (const float*)d_in[2];   // (512)
    const float* beta  = (const float*)d_in[3];   // (512)
    const float* wqkv  = (const float*)d_in[4];   // (512,1536)
    const float* wsp   = (const float*)d_in[5];   // (3,64)
    const float* wout  = (const float*)d_in[6];   // (512,512)
    const float* bout  = (const float*)d_in[7];   // (512)
    float* out = (float*)d_out;

    char* ws = (char*)d_ws;
    u16* normf = (u16*)ws;                 ws += (size_t)ROWS_ * DIM_ * 2;        // 8 MB
    u16* wqkvT = (u16*)ws;                 ws += (size_t)3 * INNER_ * DIM_ * 2;   // 1.5 MB
    u16* woutT = (u16*)ws;                 ws += (size_t)DIM_ * INNER_ * 2;       // 0.5 MB
    u16* qkv   = (u16*)ws;                 ws += (size_t)ROWS_ * 3 * INNER_ * 2;  // 24 MB
    int* idxt  = (int*)ws;                 ws += (size_t)L_ * NFR_ * N_ * NS_ * 4;// 1 MB
    u16* fres  = normf;   // alias: normf is dead after GEMM1 completes

    // prep: transpose+cvt (256 blocks) | layernorm (8192) | ball query (2048)
    prep_kernel<<<256 + ROWS_ + 2048, 256, 0, stream>>>(
        wqkv, wout, wqkvT, woutT, feat, gamma, beta, normf, xyz, idxt);
    // qkv = normf @ w_qkv : M=8192, N=1536, K=512
    gemm_bt<<<64 * 12, 256, 0, stream>>>(normf, wqkvT, qkv, nullptr,
                                         ROWS_, 3 * INNER_, DIM_, 12, 0, nullptr, nullptr);
    attn_kernel<<<ROWS_, 256, 0, stream>>>(xyz, qkv, idxt, wsp, fres);
    // out = gelu(fres @ w_out + b_out) + feature : M=8192, N=512, K=512
    gemm_bt<<<64 * 4, 256, 0, stream>>>(fres, woutT, nullptr, out,
                                        ROWS_, DIM_, INNER_, 4, 1, bout, feat);
}

// Round 9
// 182.041 us; speedup vs baseline: 1.1267x; 1.0815x over previous
//
#include <hip/hip_runtime.h>
#include <hip/hip_bf16.h>

// Problem constants (b=2, l=4, n=1024, dim=512, heads=8, dh=64, nsample=8)
// All d_in / d_out buffers are FLOAT32 (reference dtypes). Internal compute
// uses bf16 MFMA (allowed by the bf16-mode absmax threshold 0.105).
#define B_ 2
#define L_ 4
#define N_ 1024
#define DIM_ 512
#define INNER_ 512
#define HEADS_ 8
#define DH_ 64
#define NS_ 8
#define NFR_ (B_ * L_)            // 8 flat frames
#define ROWS_ (B_ * L_ * N_)      // 8192 point rows

typedef unsigned short u16;
typedef __attribute__((ext_vector_type(8))) short bf16x8;
typedef __attribute__((ext_vector_type(4))) float f32x4;

__device__ inline float bf2f(u16 u) {
    union { unsigned i; float f; } c; c.i = ((unsigned)u) << 16; return c.f;
}
__device__ inline float bflo(unsigned v) {   // low bf16 of dword -> f32
    union { unsigned i; float f; } c; c.i = v << 16; return c.f;
}
__device__ inline float bfhi(unsigned v) {   // high bf16 of dword -> f32
    union { unsigned i; float f; } c; c.i = v & 0xffff0000u; return c.f;
}
__device__ inline u16 f2bf(float x) {
    __hip_bfloat16 h = __float2bfloat16(x);  // round-to-nearest-even
    return *reinterpret_cast<u16*>(&h);
}

// Async global->LDS DMA, 16B per lane.  HW writes wave-uniform LDS base +
// lane*16; the lds pointer below must be computed so that consecutive lanes
// land at consecutive 16B slots (linear layout, NO padding - rule #21).
__device__ inline void load_lds16(const void* g, void* l) {
    __builtin_amdgcn_global_load_lds(
        (const __attribute__((address_space(1))) unsigned*)g,
        (__attribute__((address_space(3))) unsigned*)l, 16, 0, 0);
}

// 8-element bf16 dot with f32 accumulate; v_dot2_f32_bf16 when available.
#if __has_builtin(__builtin_amdgcn_fdot2_f32_bf16)
typedef __bf16 bf2v __attribute__((ext_vector_type(2)));
__device__ inline float dot8(bf16x8 a, bf16x8 b, float acc) {
    union U { bf16x8 v; bf2v p[4]; };
    U ua, ub; ua.v = a; ub.v = b;
    #pragma unroll
    for (int i = 0; i < 4; ++i)
        acc = __builtin_amdgcn_fdot2_f32_bf16(ua.p[i], ub.p[i], acc, false);
    return acc;
}
#else
__device__ inline float dot8(bf16x8 a, bf16x8 b, float acc) {
    #pragma unroll
    for (int e = 0; e < 8; ++e) acc += bf2f((u16)a[e]) * bf2f((u16)b[e]);
    return acc;
}
#endif

#define RPAD_(r) ((r) + ((r) >> 4))

// ---------------------------------------------------------------------------
// K0: fused prep kernel — transpose_cvt + layernorm + ball query.
//   blocks [0,256)            : weight transpose+cvt (0..191 wqkv, 192..255 wout)
//   blocks [256, 256+8192)    : LN row (b-256)
//   blocks [8448, 8448+2048)  : ballq block (b-8448)
// ---------------------------------------------------------------------------
__global__ __launch_bounds__(256) void prep_kernel(
    const float* __restrict__ wqkv, const float* __restrict__ wout,
    u16* __restrict__ wqkvT, u16* __restrict__ woutT,
    const float* __restrict__ feat, const float* __restrict__ gamma,
    const float* __restrict__ beta, u16* __restrict__ normf,
    const float* __restrict__ xyz, int* __restrict__ idxt)
{
    __shared__ union {
        float tile[64][65];                               // transpose: 16640 B
        struct { float rx[1088], ry[1088], rz[1088]; } bq; // ballq: 13056 B
        float red[4];                                     // ln
    } sm;

    int blk = blockIdx.x;
    int t = threadIdx.x;

    if (blk < 256) {
        // ---- weight transpose + bf16 cast (64x64 tile, pad 65) ----
        const float* src; u16* dst; int R, C, tr, tc;
        int b = blk;
        if (b < 192) { src = wqkv; dst = wqkvT; R = 512; C = 1536; tr = b / 24; tc = b % 24; }
        else { b -= 192; src = wout; dst = woutT; R = 512; C = 512; tr = b / 8; tc = b % 8; }
        int r0 = tr * 64, c0 = tc * 64;

        int rr = t >> 2, cs = (t & 3) * 16;
        const float* sp = src + (size_t)(r0 + rr) * C + c0 + cs;
        #pragma unroll
        for (int e = 0; e < 16; e += 4) {
            f32x4 v = *(const f32x4*)(sp + e);
            sm.tile[rr][cs + e + 0] = v[0];
            sm.tile[rr][cs + e + 1] = v[1];
            sm.tile[rr][cs + e + 2] = v[2];
            sm.tile[rr][cs + e + 3] = v[3];
        }
        __syncthreads();

        int c = t >> 2, ks = (t & 3) * 16;
        u16 outv[16];
        #pragma unroll
        for (int e = 0; e < 16; ++e) outv[e] = f2bf(sm.tile[ks + e][c]);
        u16* dp = dst + (size_t)(c0 + c) * R + r0 + ks;
        *(bf16x8*)(dp)     = *(bf16x8*)&outv[0];
        *(bf16x8*)(dp + 8) = *(bf16x8*)&outv[8];

    } else if (blk < 256 + ROWS_) {
        // ---- LayerNorm over channel dim (512) -> bf16 ----
        int row = blk - 256;
        const float* fr = feat + (size_t)row * DIM_;
        float x0 = fr[t], x1 = fr[t + 256];

        float s = x0 + x1;
        #pragma unroll
        for (int off = 32; off; off >>= 1) s += __shfl_xor(s, off, 64);
        if ((t & 63) == 0) sm.red[t >> 6] = s;
        __syncthreads();
        float mu = (sm.red[0] + sm.red[1] + sm.red[2] + sm.red[3]) * (1.0f / 512.0f);
        __syncthreads();

        float d0 = x0 - mu, d1 = x1 - mu;
        float q = d0 * d0 + d1 * d1;
        #pragma unroll
        for (int off = 32; off; off >>= 1) q += __shfl_xor(q, off, 64);
        if ((t & 63) == 0) sm.red[t >> 6] = q;
        __syncthreads();
        float var = (sm.red[0] + sm.red[1] + sm.red[2] + sm.red[3]) * (1.0f / 512.0f);
        float inv = rsqrtf(var + 1e-5f);

        normf[(size_t)row * DIM_ + t]       = f2bf(d0 * inv * gamma[t]       + beta[t]);
        normf[(size_t)row * DIM_ + t + 256] = f2bf(d1 * inv * gamma[t + 256] + beta[t + 256]);

    } else {
        // ---- ball query (wave-parallel, staging-amortized) ----
        #pragma clang fp contract(off)
        int bb = blk - (256 + ROWS_);
        int chunk = bb & 255;           // 2048 blocks: (bi*4+jf)*256 + chunk
        int combo = bb >> 8;
        int jf = combo & 3;
        int bi = combo >> 2;

        const float* ref = xyz + (size_t)((bi * L_ + jf) * N_) * 3;
        for (int p = t; p < N_; p += 256) {
            sm.bq.rx[RPAD_(p)] = ref[p * 3 + 0];
            sm.bq.ry[RPAD_(p)] = ref[p * 3 + 1];
            sm.bq.rz[RPAD_(p)] = ref[p * 3 + 2];
        }
        __syncthreads();

        int wave = t >> 6;
        int lane = t & 63;
        int n = chunk * 4 + wave;
        int base = lane * 17;           // RPAD_(lane*16)
        int r0 = lane * 16;

        for (int qi = 0; qi < L_; ++qi) {
            const float* qp = xyz + (size_t)((bi * L_ + qi) * N_ + n) * 3;
            float qx = qp[0], qy = qp[1], qz = qp[2];

            unsigned mask = 0;
            #pragma unroll
            for (int j = 0; j < 16; ++j) {
                float dx = qx - sm.bq.rx[base + j];
                float dy = qy - sm.bq.ry[base + j];
                float dz = qz - sm.bq.rz[base + j];
                float d2 = dx * dx + dy * dy;
                d2 = d2 + dz * dz;
                if (d2 < 0.04f) mask |= (1u << j);
            }

            int cnt = __popc(mask);
            int x = cnt;
            #pragma unroll
            for (int off = 1; off < 64; off <<= 1) {
                int y = __shfl_up(x, off, 64);
                if (lane >= off) x += y;
            }
            int pre = x - cnt;                       // exclusive prefix
            int total = __shfl(x, 63, 64);           // total in-radius count

            int localFirst = mask ? (r0 + __builtin_ctz(mask)) : 0x7fffffff;
            int gfirst = localFirst;
            #pragma unroll
            for (int off = 32; off; off >>= 1) gfirst = min(gfirst, __shfl_xor(gfirst, off, 64));

            int* o = idxt + ((size_t)((qi * B_ + bi) * N_ + n)) * 32 + jf * NS_;

            unsigned m = mask;
            int pos = pre;
            while (m && pos < NS_) {
                int j = __builtin_ctz(m);
                o[pos] = r0 + j;
                m &= m - 1;
                ++pos;
            }
            if (lane == 0) {
                int padv = (total > 0) ? gfirst : 0;
                for (int s = (total < NS_ ? total : NS_); s < NS_; ++s) o[s] = padv;
            }
        }
    }
}

// ---------------------------------------------------------------------------
// K2/K5: MFMA bf16 GEMM, C[M,N] = A[M,K] @ Bt[N,K]^T.
// Round 16: 8-wave (512-thread) blocks, 128x128 tile, BK=32, double-buffered.
// r8 post-mortem: dbuf alone was neutral -- the barrier's implicit vmcnt(0)
// exposes ~600cy/step and 4-wave blocks x 3 blocks/CU = only 3 waves/SIMD
// of TLP to cover it (r7: MfmaUtil 3.2%, VALUBusy 8.9%, CU mostly idle).
// 512-thread blocks double per-CU wave count (6/SIMD): each wave owns a
// 64x32 sub-tile (2Mx4N wave grid, acc 4x2 = 32 VGPR), staging is ONE 16B
// load per thread per operand (512 x 16B = exactly one 8 KB tile).  Sync
// structure identical to the verified r8 loop.  LDS 32 KB (5 blocks/CU cap).
// mode 0: Cb16 = bf16(acc)                          (qkv, bf16 ws)
// mode 1: Cf32 = gelu(acc + bias) + resid           (final output, f32)
// ---------------------------------------------------------------------------
__global__ __launch_bounds__(512) void gemm_bt(
    const u16* __restrict__ A, const u16* __restrict__ Bt,
    u16* __restrict__ Cb16, float* __restrict__ Cf32,
    int M, int N, int K, int nb128, int mode,
    const float* __restrict__ bias, const float* __restrict__ resid)
{
    __shared__ u16 As[2][128 * 32];   // linear, 2 x 8 KB per operand
    __shared__ u16 Bs[2][128 * 32];

    int bx = blockIdx.x % nb128;
    int by = blockIdx.x / nb128;
    int m0 = by * 128, n0 = bx * 128;
    int t = threadIdx.x;               // 0..511
    int wave = t >> 6, lane = t & 63;
    int lr = lane & 15, quad = lane >> 4;
    int wm = (wave >> 2) * 64;         // 2 waves in M: 0, 64
    int wn = (wave & 3) * 32;          // 4 waves in N: 0, 32, 64, 96

    // staging coords: thread t covers row t>>2 (0..127), 8-col chunk (t&3)*8.
    // LDS u16 offset t*8: within a wave = wave*1024B + lane*16B -- exactly
    // the DMA's wave-uniform base + lane*16 ordering (linear, rule #21).
    int rs = t >> 2;
    int kcs = (t & 3) * 8;

    f32x4 acc[4][2];
    #pragma unroll
    for (int i = 0; i < 4; ++i)
        #pragma unroll
        for (int j = 0; j < 2; ++j)
            acc[i][j] = {0.f, 0.f, 0.f, 0.f};

    int NT = K >> 5;                   // 16 K-steps for K=512

    // prologue: stage tile 0 into buf 0 (one load per thread per operand)
    load_lds16(A  + (size_t)(m0 + rs) * K + kcs, &As[0][t * 8]);
    load_lds16(Bt + (size_t)(n0 + rs) * K + kcs, &Bs[0][t * 8]);
    __syncthreads();

    int cur = 0;
    for (int kt = 0; kt < NT; ++kt) {
        // issue next tile's staging FIRST (latency overlaps this tile's math)
        if (kt + 1 < NT) {
            int k0 = (kt + 1) << 5;
            load_lds16(A  + (size_t)(m0 + rs) * K + k0 + kcs, &As[cur ^ 1][t * 8]);
            load_lds16(Bt + (size_t)(n0 + rs) * K + k0 + kcs, &Bs[cur ^ 1][t * 8]);
        }

        bf16x8 af[4], bfr[2];
        #pragma unroll
        for (int mb = 0; mb < 4; ++mb)
            af[mb] = *(const bf16x8*)&As[cur][(wm + mb * 16 + lr) * 32 + quad * 8];
        #pragma unroll
        for (int nb = 0; nb < 2; ++nb)
            bfr[nb] = *(const bf16x8*)&Bs[cur][(wn + nb * 16 + lr) * 32 + quad * 8];
        #pragma unroll
        for (int mb = 0; mb < 4; ++mb)
            #pragma unroll
            for (int nb = 0; nb < 2; ++nb)
                acc[mb][nb] = __builtin_amdgcn_mfma_f32_16x16x32_bf16(
                    af[mb], bfr[nb], acc[mb][nb], 0, 0, 0);

        __syncthreads();   // implicit vmcnt(0)+lgkmcnt(0): prefetch landed,
                           // all waves done reading buf[cur]
        cur ^= 1;
    }

    #pragma unroll
    for (int mb = 0; mb < 4; ++mb) {
        #pragma unroll
        for (int nb = 0; nb < 2; ++nb) {
            int col = n0 + wn + nb * 16 + lr;
            #pragma unroll
            for (int r = 0; r < 4; ++r) {
                int row = m0 + wm + mb * 16 + quad * 4 + r;
                float x = acc[mb][nb][r];
                if (mode == 1) {
                    x += bias[col];
                    float gl = 0.5f * x * (1.0f + erff(x * 0.70710678118654752f));
                    Cf32[(size_t)row * N + col] = gl + resid[(size_t)row * N + col];
                } else {
                    Cb16[(size_t)row * N + col] = f2bf(x);
                }
            }
        }
    }
}

// ---------------------------------------------------------------------------
// K4: attention, request-coalesced (round-3 configuration, best-measured;
// L3-BW-bound at ~35 us: 533 MB gather / ~15 TB/s -- at its floor for this
// access pattern; r12/r13/r14 restructures all neutral-to-negative).
// ---------------------------------------------------------------------------
__global__ __launch_bounds__(256, 4) void attn_kernel(
    const float* __restrict__ xyz, const u16* __restrict__ qkv,
    const int* __restrict__ idxt, const float* __restrict__ wsp,
    u16* __restrict__ fres)
{
    int x = blockIdx.x & 7;             // XCD swizzle retained (FETCH 100->35 MB)
    int bi = x >> 2;
    int qi = x & 3;
    int n = blockIdx.x >> 3;

    int t = threadIdx.x;
    int wave = t >> 6, lane = t & 63;

    int qrow = (bi * L_ + qi) * N_ + n;                  // xyz/qkv row
    int qq = (qi * B_ + bi) * N_ + n;                    // idxt row

    __shared__ int grow_s[32];
    __shared__ float nx_s[32], ny_s[32], nz_s[32];
    __shared__ float lg_s[HEADS_][33];                   // pad 33: conflict-free
    __shared__ float a_s[HEADS_][32];
    __shared__ float da_s[HEADS_][3];

    // Per-lane Q fragment: lane l holds q[qrow][l*8 .. l*8+8) -> head l>>3.
    bf16x8 qf = *(const bf16x8*)(qkv + (size_t)qrow * 1536 + lane * 8);

    // 32 lanes resolve the gathered rows + neighbor xyz once per block.
    if (t < 32) {
        int idx = idxt[(size_t)qq * 32 + t];             // one coalesced 128B load
        int jf = t >> 3;
        int kr = (bi * L_ + jf) * N_ + idx;
        grow_s[t] = kr;
        nx_s[t] = xyz[(size_t)kr * 3 + 0];
        ny_s[t] = xyz[(size_t)kr * 3 + 1];
        nz_s[t] = xyz[(size_t)kr * 3 + 2];
    }
    __syncthreads();

    // --- QK^T: wave w owns neighbor slots j = w*8 + r.  One coalesced 1 KB
    // K-row load per slot (SGPR base + lane*16B), batched before use. ---
    bf16x8 kf[8];
    #pragma unroll
    for (int r = 0; r < 8; ++r) {
        int kr = __builtin_amdgcn_readfirstlane(grow_s[wave * 8 + r]);
        const char* kbase = (const char*)qkv + (size_t)kr * 3072 + 1024;  // K block
        kf[r] = *(const bf16x8*)(kbase + lane * 16);
    }
    __builtin_amdgcn_sched_barrier(0);   // all 8 row loads issued before use

    #pragma unroll
    for (int r = 0; r < 8; ++r) {
        float p = dot8(kf[r], qf, 0.f);
        p += __shfl_xor(p, 1, 64);       // reduce 8-dim partials within the
        p += __shfl_xor(p, 2, 64);       // 8-lane head group -> full dot64
        p += __shfl_xor(p, 4, 64);
        if ((lane & 7) == 0) lg_s[lane >> 3][wave * 8 + r] = p * 0.125f;  // dh^-0.5
    }
    __syncthreads();

    // --- softmax + disp-max in the original (h, j) lane mapping ---
    int hh = lane >> 5;
    int j = lane & 31;
    int h = wave * 2 + hh;

    float lg = lg_s[h][j];
    float mx = lg;
    #pragma unroll
    for (int off = 16; off; off >>= 1) mx = fmaxf(mx, __shfl_xor(mx, off, 64));
    float e = expf(lg - mx);
    float sum = e;
    #pragma unroll
    for (int off = 16; off; off >>= 1) sum += __shfl_xor(sum, off, 64);
    float a = e / sum;
    a_s[h][j] = a;

    float qx = xyz[(size_t)qrow * 3 + 0];
    float qy = xyz[(size_t)qrow * 3 + 1];
    float qz = xyz[(size_t)qrow * 3 + 2];
    float tx = a * (nx_s[j] - qx);
    float ty = a * (ny_s[j] - qy);
    float tz = a * (nz_s[j] - qz);
    #pragma unroll
    for (int off = 16; off; off >>= 1) {
        tx = fmaxf(tx, __shfl_xor(tx, off, 64));
        ty = fmaxf(ty, __shfl_xor(ty, off, 64));
        tz = fmaxf(tz, __shfl_xor(tz, off, 64));
    }
    if (j == 0) { da_s[h][0] = tx; da_s[h][1] = ty; da_s[h][2] = tz; }

    __syncthreads();

    // --- Phase C: V gather (coalesced), SGPR-base addressed. ---
    int dd = j * 2;
    unsigned vbyte = (1024u + (unsigned)h * 64u + (unsigned)dd) * 2u;  // V block col
    unsigned vv[32];
    #pragma unroll
    for (int s = 0; s < 32; ++s) {
        int r = __builtin_amdgcn_readfirstlane(grow_s[s]);
        const char* vbase = (const char*)qkv + (size_t)r * 3072;       // uniform
        vv[s] = *(const unsigned*)(vbase + vbyte);
    }
    __builtin_amdgcn_sched_barrier(0);   // all 32 loads issued before any use

    float o0 = 0.f, o1 = 0.f;
    #pragma unroll
    for (int s = 0; s < 32; ++s) {
        float at = a_s[h][s];
        o0 += at * bflo(vv[s]);
        o1 += at * bfhi(vv[s]);
    }
    float dax = da_s[h][0], day = da_s[h][1], daz = da_s[h][2];
    float sp0 = dax * wsp[dd]     + day * wsp[64 + dd]     + daz * wsp[128 + dd];
    float sp1 = dax * wsp[dd + 1] + day * wsp[64 + dd + 1] + daz * wsp[128 + dd + 1];

    u16* op = fres + (size_t)qrow * INNER_ + h * 64 + dd;
    unsigned outw = (unsigned)f2bf(o0 + sp0) | ((unsigned)f2bf(o1 + sp1) << 16);
    *(unsigned*)op = outw;
}

// ---------------------------------------------------------------------------
extern "C" void kernel_launch(void* const* d_in, const int* in_sizes, int n_in,
                              void* d_out, int out_size, void* d_ws, size_t ws_size,
                              hipStream_t stream) {
    const float* xyz   = (const float*)d_in[0];   // (2,4,1024,3)
    const float* feat  = (const float*)d_in[1];   // (2,4,1024,512)
    const float* gamma = (const float*)d_in[2];   // (512)
    const float* beta  = (const float*)d_in[3];   // (512)
    const float* wqkv  = (const float*)d_in[4];   // (512,1536)
    const float* wsp   = (const float*)d_in[5];   // (3,64)
    const float* wout  = (const float*)d_in[6];   // (512,512)
    const float* bout  = (const float*)d_in[7];   // (512)
    float* out = (float*)d_out;

    char* ws = (char*)d_ws;
    u16* normf = (u16*)ws;                 ws += (size_t)ROWS_ * DIM_ * 2;        // 8 MB
    u16* wqkvT = (u16*)ws;                 ws += (size_t)3 * INNER_ * DIM_ * 2;   // 1.5 MB
    u16* woutT = (u16*)ws;                 ws += (size_t)DIM_ * INNER_ * 2;       // 0.5 MB
    u16* qkv   = (u16*)ws;                 ws += (size_t)ROWS_ * 3 * INNER_ * 2;  // 24 MB
    int* idxt  = (int*)ws;                 ws += (size_t)L_ * NFR_ * N_ * NS_ * 4;// 1 MB
    u16* fres  = normf;   // alias: normf is dead after GEMM1 completes

    // prep: transpose+cvt (256 blocks) | layernorm (8192) | ball query (2048)
    prep_kernel<<<256 + ROWS_ + 2048, 256, 0, stream>>>(
        wqkv, wout, wqkvT, woutT, feat, gamma, beta, normf, xyz, idxt);
    // qkv = normf @ w_qkv : M=8192, N=1536, K=512  (512-thread blocks)
    gemm_bt<<<64 * 12, 512, 0, stream>>>(normf, wqkvT, qkv, nullptr,
                                         ROWS_, 3 * INNER_, DIM_, 12, 0, nullptr, nullptr);
    attn_kernel<<<ROWS_, 256, 0, stream>>>(xyz, qkv, idxt, wsp, fres);
    // out = gelu(fres @ w_out + b_out) + feature : M=8192, N=512, K=512
    gemm_bt<<<64 * 4, 512, 0, stream>>>(fres, woutT, nullptr, out,
                                        ROWS_, DIM_, INNER_, 4, 1, bout, feat);
}